// Round 3
// baseline (458.241 us; speedup 1.0000x reference)
//
#include <hip/hip_runtime.h>

typedef __bf16 bf16_t;
typedef bf16_t bf16x8 __attribute__((ext_vector_type(8)));
typedef bf16_t bf16x4v __attribute__((ext_vector_type(4)));
typedef float f32x4 __attribute__((ext_vector_type(4)));

#define GLDS16(g, l) __builtin_amdgcn_global_load_lds( \
    (const __attribute__((address_space(1))) void*)(g), \
    (__attribute__((address_space(3))) void*)(l), 16, 0, 0)

// Problem constants
#define BB 2
#define SEQ 2048
#define DMODEL 2048
#define RDIM 512
#define NH 16
#define DNOPE 128
#define DROPE 64
#define DVDIM 128
#define MROWS 4096           // BB*SEQ
#define DQK 192              // DNOPE+DROPE

// ---------------- prep kernels ----------------

__global__ __launch_bounds__(256) void cast_x_kernel(const float* __restrict__ x,
                                                     bf16_t* __restrict__ xb) {
    int idx = blockIdx.x * 256 + threadIdx.x;
    float4 v = ((const float4*)x)[idx];
    bf16x4v o;
    o[0] = (bf16_t)v.x; o[1] = (bf16_t)v.y; o[2] = (bf16_t)v.z; o[3] = (bf16_t)v.w;
    ((bf16x4v*)xb)[idx] = o;
}

// W (K x N) f32 -> WT (N x K) bf16, tiled transpose
__global__ __launch_bounds__(256) void wtrans_kernel(const float* __restrict__ W,
                                                     bf16_t* __restrict__ WT,
                                                     int K, int N) {
    __shared__ float t[32][33];
    int n0 = blockIdx.x * 32, k0 = blockIdx.y * 32;
    int tx = threadIdx.x & 31, ty = threadIdx.x >> 5;  // ty 0..7
    #pragma unroll
    for (int i = 0; i < 4; ++i)
        t[ty + i*8][tx] = W[(size_t)(k0 + ty + i*8) * N + n0 + tx];
    __syncthreads();
    #pragma unroll
    for (int i = 0; i < 4; ++i)
        WT[(size_t)(n0 + ty + i*8) * K + k0 + tx] = (bf16_t)t[tx][ty + i*8];
}

__global__ __launch_bounds__(256) void rope_table_kernel(const float* __restrict__ freqs,
                                                         float* __restrict__ costab,
                                                         float* __restrict__ sintab) {
    int idx = blockIdx.x * 256 + threadIdx.x;   // SEQ*32 exact
    float f = freqs[idx];
    costab[idx] = cosf(f);
    sintab[idx] = sinf(f);
}

__global__ __launch_bounds__(256) void rmsnorm_kernel(const float* __restrict__ kvf,
                                                      const float* __restrict__ gkv,
                                                      bf16_t* __restrict__ kvb) {
    int m = blockIdx.x;
    int tid = threadIdx.x;
    const float* rowp = kvf + (size_t)m * RDIM;
    float2 v = *(const float2*)(rowp + tid * 2);
    float ss = v.x * v.x + v.y * v.y;
    #pragma unroll
    for (int d = 1; d < 64; d <<= 1) ss += __shfl_xor(ss, d, 64);
    __shared__ float red[4];
    if ((tid & 63) == 0) red[tid >> 6] = ss;
    __syncthreads();
    float tot = red[0] + red[1] + red[2] + red[3];
    float scale = rsqrtf(tot * (1.0f / RDIM) + 1e-6f);
    bf16_t* orow = kvb + (size_t)m * RDIM;
    orow[tid*2]     = (bf16_t)(v.x * scale * gkv[tid*2]);
    orow[tid*2 + 1] = (bf16_t)(v.y * scale * gkv[tid*2 + 1]);
}

// ---------------- GEMM: C(MxN) = A(MxK) * Bt(NxK)^T, bf16 in, OutT out --------
// 128x128 tile, BK=64, 4 waves (2x2), global_load_lds staging with XOR swizzle.

template<typename OutT>
__global__ __launch_bounds__(256, 2) void gemm_bt(const bf16_t* __restrict__ A,
                                                  const bf16_t* __restrict__ Bt,
                                                  OutT* __restrict__ C,
                                                  int M, int N, int K) {
    __shared__ __align__(16) char ldsA[128 * 128];   // 128 rows x 128B (64 bf16)
    __shared__ __align__(16) char ldsB[128 * 128];
    int tid = threadIdx.x;
    int lane = tid & 63, wave = tid >> 6;
    int n0 = blockIdx.x * 128, m0 = blockIdx.y * 128;
    int wr = wave >> 1, wc = wave & 1;
    int g = lane >> 4, c = lane & 15;
    f32x4 acc[4][4] = {};

    int srow = tid >> 3;         // 0..31: row within 4KB staging slab
    int sch = tid & 7;           // chunk (16B) within 128B row

    int nkt = K >> 6;
    for (int kt = 0; kt < nkt; ++kt) {
        int k0 = kt << 6;
        #pragma unroll
        for (int j = 0; j < 4; ++j) {
            int row = j * 32 + srow;
            int csrc = sch ^ (row & 7);     // pre-swizzled source chunk
            const char* gA = (const char*)(A + (size_t)(m0 + row) * K + k0) + csrc * 16;
            const char* gB = (const char*)(Bt + (size_t)(n0 + row) * K + k0) + csrc * 16;
            char* lA = ldsA + j * 4096 + wave * 1024;
            char* lB = ldsB + j * 4096 + wave * 1024;
            GLDS16(gA, lA);
            GLDS16(gB, lB);
        }
        __syncthreads();
        #pragma unroll
        for (int kk = 0; kk < 2; ++kk) {
            int kb = kk * 64 + g * 16;      // byte offset within row
            bf16x8 aF[4], bF[4];
            #pragma unroll
            for (int m = 0; m < 4; ++m) {
                int row = wr * 64 + m * 16 + c;
                aF[m] = *(const bf16x8*)(ldsA + row * 128 + (kb ^ ((row & 7) << 4)));
            }
            #pragma unroll
            for (int n = 0; n < 4; ++n) {
                int row = wc * 64 + n * 16 + c;
                bF[n] = *(const bf16x8*)(ldsB + row * 128 + (kb ^ ((row & 7) << 4)));
            }
            #pragma unroll
            for (int m = 0; m < 4; ++m)
                #pragma unroll
                for (int n = 0; n < 4; ++n)
                    acc[m][n] = __builtin_amdgcn_mfma_f32_16x16x32_bf16(aF[m], bF[n], acc[m][n], 0, 0, 0);
        }
        __syncthreads();
    }
    // epilogue: C/D layout col=lane&15, row=(lane>>4)*4+i
    #pragma unroll
    for (int m = 0; m < 4; ++m) {
        int grow = m0 + wr * 64 + m * 16 + g * 4;
        #pragma unroll
        for (int n = 0; n < 4; ++n) {
            int gcol = n0 + wc * 64 + n * 16 + c;
            #pragma unroll
            for (int i = 0; i < 4; ++i)
                C[(size_t)(grow + i) * N + gcol] = (OutT)acc[m][n][i];
        }
    }
}

// ---------------- pack / rope kernels ----------------

// qfull [M][3072] -> qpack [BH][S][192] (nope part, d<128)
__global__ __launch_bounds__(256) void pack_q_nope(const bf16_t* __restrict__ qfull,
                                                   bf16_t* __restrict__ qpack) {
    int idx = blockIdx.x * 256 + threadIdx.x;      // M*16*16
    int m = idx >> 8, rest = idx & 255;
    int h = rest >> 4, ch = rest & 15;
    int b = m >> 11, s = m & 2047;
    bf16x8 v = *(const bf16x8*)(qfull + (size_t)m * 3072 + h * 128 + ch * 8);
    *(bf16x8*)(qpack + ((size_t)(b * NH + h) * SEQ + s) * DQK + ch * 8) = v;
}

__global__ __launch_bounds__(256) void pack_q_rope(const bf16_t* __restrict__ qfull,
                                                   bf16_t* __restrict__ qpack,
                                                   const float* __restrict__ costab,
                                                   const float* __restrict__ sintab) {
    int idx = blockIdx.x * 256 + threadIdx.x;      // M*16*32
    int m = idx >> 9, h = (idx >> 5) & 15, j = idx & 31;
    int b = m >> 11, s = m & 2047;
    const bf16_t* src = qfull + (size_t)m * 3072 + 2048 + h * 64 + 2 * j;
    float xr = (float)src[0], xi = (float)src[1];
    float cs = costab[s * 32 + j], sn = sintab[s * 32 + j];
    bf16_t* dst = qpack + ((size_t)(b * NH + h) * SEQ + s) * DQK + DNOPE + 2 * j;
    dst[0] = (bf16_t)(xr * cs - xi * sn);
    dst[1] = (bf16_t)(xr * sn + xi * cs);
}

// kvout [M][5120]: cols 0..3071 = k_full (h*192+d), 3072.. = v (h*128+dv)
__global__ __launch_bounds__(256) void pack_k_nope(const bf16_t* __restrict__ kvout,
                                                   bf16_t* __restrict__ kpack) {
    int idx = blockIdx.x * 256 + threadIdx.x;
    int m = idx >> 8, rest = idx & 255;
    int h = rest >> 4, ch = rest & 15;
    int b = m >> 11, s = m & 2047;
    bf16x8 v = *(const bf16x8*)(kvout + (size_t)m * 5120 + h * DQK + ch * 8);
    *(bf16x8*)(kpack + ((size_t)(b * NH + h) * SEQ + s) * DQK + ch * 8) = v;
}

__global__ __launch_bounds__(256) void pack_k_rope(const bf16_t* __restrict__ kvout,
                                                   bf16_t* __restrict__ kpack,
                                                   const float* __restrict__ costab,
                                                   const float* __restrict__ sintab) {
    int idx = blockIdx.x * 256 + threadIdx.x;
    int m = idx >> 9, h = (idx >> 5) & 15, j = idx & 31;
    int b = m >> 11, s = m & 2047;
    const bf16_t* src = kvout + (size_t)m * 5120 + h * DQK + DNOPE + 2 * j;
    float xr = (float)src[0], xi = (float)src[1];
    float cs = costab[s * 32 + j], sn = sintab[s * 32 + j];
    bf16_t* dst = kpack + ((size_t)(b * NH + h) * SEQ + s) * DQK + DNOPE + 2 * j;
    dst[0] = (bf16_t)(xr * cs - xi * sn);
    dst[1] = (bf16_t)(xr * sn + xi * cs);
}

// v part of kvout -> vt [BH][128][SEQ]  (transposed for PV B-fragments)
__global__ __launch_bounds__(256) void pack_v_kernel(const bf16_t* __restrict__ kvout,
                                                     bf16_t* __restrict__ vt) {
    __shared__ bf16_t t[64][144];
    int blk = blockIdx.x;                 // 32 bh * 32 stiles
    int bh = blk >> 5, st = blk & 31;
    int s0 = st * 64;
    int b = bh >> 4, h = bh & 15;
    int tid = threadIdx.x;
    #pragma unroll
    for (int i = 0; i < 4; ++i) {
        int id = i * 256 + tid;           // 1024: 64 rows x 16 chunks
        int row = id >> 4, ch = id & 15;
        bf16x8 v = *(const bf16x8*)(kvout + (size_t)(b * SEQ + s0 + row) * 5120 + 3072 + h * 128 + ch * 8);
        *(bf16x8*)&t[row][ch * 8] = v;
    }
    __syncthreads();
    #pragma unroll
    for (int i = 0; i < 4; ++i) {
        int id = i * 256 + tid;           // 1024: 128 dv x 8 chunks
        int dv = id >> 3, sc = id & 7;
        bf16x8 v;
        #pragma unroll
        for (int jj = 0; jj < 8; ++jj) v[jj] = t[sc * 8 + jj][dv];
        *(bf16x8*)(vt + ((size_t)bh * 128 + dv) * SEQ + s0 + sc * 8) = v;
    }
}

// ---------------- flash attention v3 ----------------
// Q,K: [BH][S][192] bf16; VT: [BH][128][S] bf16; O: [M][2048] bf16 (col=h*128+dv)
// 1024 blocks (bh x qtile), heavy-first within each XCD's 4 heads.
// 4 waves x 16 q-rows, KV tile 64. K via global_load_lds (swizzled source,
// linear dest, swizzled read). V prefetched to REGISTERS at tile start so its
// L2 latency hides under K staging + QK + softmax.

__global__ __launch_bounds__(256, 3) void attn_kernel(const bf16_t* __restrict__ Q,
                                                      const bf16_t* __restrict__ Kp,
                                                      const bf16_t* __restrict__ VT,
                                                      bf16_t* __restrict__ O) {
    __shared__ __align__(16) char ldsK[64 * 384];     // [64][192] bf16, linear (swizzled content)
    __shared__ __align__(16) char ldsP[4 * 16 * 176]; // per-wave [16][64+24pad] bf16
    int tid = threadIdx.x, lane = tid & 63, wave = tid >> 6;
    int g = lane >> 4, c = lane & 15;

    // XCD-aware mapping: xcd = bid&7 owns 4 heads; qt descending in dispatch
    // order so heavy blocks start first (nt = qt+1 ranges 32..1).
    int bid = blockIdx.x;                // 0..1023
    int xcd = bid & 7, idx = bid >> 3;   // idx 0..127
    int bh = xcd * 4 + (idx & 3);        // 0..31
    int qt = 31 - (idx >> 2);            // 31..0
    int b = bh >> 4, h = bh & 15;
    int q0 = qt * 64;
    int nt = qt + 1;

    const bf16_t* Qb = Q + (size_t)bh * SEQ * DQK;
    const bf16_t* Kb = Kp + (size_t)bh * SEQ * DQK;
    const bf16_t* Vb = VT + (size_t)bh * 128 * SEQ;
    char* ldsPw = ldsP + wave * (16 * 176);

    // staging map: 1536 chunks of 16B; id -> (row=id/24, ch=id%24); source chunk
    // XORed so linear LDS + swizzled read composes to identity (rule #21).
    int soff[6];
    #pragma unroll
    for (int i2 = 0; i2 < 6; ++i2) {
        int id = i2 * 256 + tid;
        int row = id / 24, ch = id - row * 24;
        soff[i2] = row * 384 + (ch ^ (row & 7)) * 16;
    }
    const float sc = 0.0721687836f * 1.44269504f;   // 1/sqrt(192) * log2(e)

    bf16x8 qf[6];
    {
        const bf16_t* qrow = Qb + (size_t)(q0 + wave * 16 + c) * DQK + g * 8;
        #pragma unroll
        for (int kk = 0; kk < 6; ++kk) qf[kk] = *(const bf16x8*)(qrow + kk * 32);
    }
    float m_run[4], l_run[4];
    f32x4 accO[8] = {};
    #pragma unroll
    for (int i = 0; i < 4; ++i) { m_run[i] = -3.0e38f; l_run[i] = 0.f; }

    #pragma unroll 1
    for (int t = 0; t < nt; ++t) {
        // issue K tile staging (24KB) via global_load_lds
        const char* Kt = (const char*)Kb + (size_t)t * 24576;
        #pragma unroll
        for (int i2 = 0; i2 < 6; ++i2)
            GLDS16(Kt + soff[i2], ldsK + i2 * 4096 + wave * 1024);

        // prefetch V tile into registers (issued before the barrier so L2
        // latency overlaps K staging; consumed only at PV)
        const bf16_t* Vt = Vb + (size_t)t * 64;
        bf16x8 vf[16];
        #pragma unroll
        for (int n = 0; n < 8; ++n) {
            const bf16_t* vrow = Vt + (size_t)(n * 16 + c) * SEQ + g * 8;
            vf[2 * n]     = *(const bf16x8*)(vrow);
            vf[2 * n + 1] = *(const bf16x8*)(vrow + 32);
        }
        __syncthreads();

        // QK^T: per wave 16 q-rows x 64 k
        f32x4 accS[4] = {};
        __builtin_amdgcn_s_setprio(1);
        #pragma unroll
        for (int kk = 0; kk < 6; ++kk) {
            int kb = kk * 64 + g * 16;
            #pragma unroll
            for (int n = 0; n < 4; ++n) {
                int row = n * 16 + c;
                bf16x8 kf = *(const bf16x8*)(ldsK + row * 384 + (kb ^ ((row & 7) << 4)));
                accS[n] = __builtin_amdgcn_mfma_f32_16x16x32_bf16(qf[kk], kf, accS[n], 0, 0, 0);
            }
        }
        __builtin_amdgcn_s_setprio(0);

        // scale + causal mask (only diagonal tile is partial: KVBLK==QBLK==64)
        bool diag = (t == nt - 1);
        #pragma unroll
        for (int n = 0; n < 4; ++n)
            #pragma unroll
            for (int i = 0; i < 4; ++i) {
                float v = accS[n][i] * sc;
                if (diag && (n * 16 + c > wave * 16 + g * 4 + i)) v = -1e30f;
                accS[n][i] = v;
            }
        // online softmax, rows = g*4+i, cols spread over n-frags and c-lanes
        #pragma unroll
        for (int i = 0; i < 4; ++i) {
            float mx = fmaxf(fmaxf(accS[0][i], accS[1][i]), fmaxf(accS[2][i], accS[3][i]));
            #pragma unroll
            for (int d = 1; d < 16; d <<= 1) mx = fmaxf(mx, __shfl_xor(mx, d, 64));
            float mnew = fmaxf(m_run[i], mx);
            float alpha = exp2f(m_run[i] - mnew);
            m_run[i] = mnew;
            float rs = 0.f;
            #pragma unroll
            for (int n = 0; n < 4; ++n) {
                float p = exp2f(accS[n][i] - mnew);
                accS[n][i] = p;
                rs += p;
            }
            #pragma unroll
            for (int d = 1; d < 16; d <<= 1) rs += __shfl_xor(rs, d, 64);
            l_run[i] = l_run[i] * alpha + rs;
            #pragma unroll
            for (int n = 0; n < 8; ++n) accO[n][i] *= alpha;
        }
        // P (C-frag) -> per-wave LDS -> A-frag
        #pragma unroll
        for (int n = 0; n < 4; ++n)
            #pragma unroll
            for (int i = 0; i < 4; ++i)
                *(bf16_t*)(ldsPw + (g * 4 + i) * 176 + (n * 16 + c) * 2) = (bf16_t)accS[n][i];
        bf16x8 pf0 = *(const bf16x8*)(ldsPw + c * 176 + g * 16);
        bf16x8 pf1 = *(const bf16x8*)(ldsPw + c * 176 + 64 + g * 16);

        // PV: V already in registers
        __builtin_amdgcn_s_setprio(1);
        #pragma unroll
        for (int n = 0; n < 8; ++n) {
            accO[n] = __builtin_amdgcn_mfma_f32_16x16x32_bf16(pf0, vf[2 * n],     accO[n], 0, 0, 0);
            accO[n] = __builtin_amdgcn_mfma_f32_16x16x32_bf16(pf1, vf[2 * n + 1], accO[n], 0, 0, 0);
        }
        __builtin_amdgcn_s_setprio(0);
        __syncthreads();   // all waves done with ldsK before next stage
    }
    // write O
    float inv_l[4];
    #pragma unroll
    for (int i = 0; i < 4; ++i) inv_l[i] = 1.0f / l_run[i];
    #pragma unroll
    for (int n = 0; n < 8; ++n) {
        int gcol = h * 128 + n * 16 + c;
        #pragma unroll
        for (int i = 0; i < 4; ++i) {
            int mrow = b * SEQ + q0 + wave * 16 + g * 4 + i;
            O[(size_t)mrow * 2048 + gcol] = (bf16_t)(accO[n][i] * inv_l[i]);
        }
    }
}

// ---------------- launch ----------------

extern "C" void kernel_launch(void* const* d_in, const int* in_sizes, int n_in,
                              void* d_out, int out_size, void* d_ws, size_t ws_size,
                              hipStream_t stream) {
    const float* x     = (const float*)d_in[0];
    const float* freqs = (const float*)d_in[1];
    const float* w_kv  = (const float*)d_in[2];
    const float* g_kv  = (const float*)d_in[3];
    const float* w_k   = (const float*)d_in[4];
    const float* w_v   = (const float*)d_in[5];
    const float* w_qn  = (const float*)d_in[6];
    const float* w_qr  = (const float*)d_in[7];
    const float* w_o   = (const float*)d_in[8];
    float* out = (float*)d_out;

    char* ws = (char*)d_ws;
    size_t off = 0;
    auto alloc = [&](size_t bytes) { char* p = ws + off; off += (bytes + 255) & ~(size_t)255; return p; };
    bf16_t* xb     = (bf16_t*)alloc((size_t)MROWS * DMODEL * 2);
    bf16_t* wkvT   = (bf16_t*)alloc((size_t)RDIM * DMODEL * 2);
    bf16_t* wkvwT  = (bf16_t*)alloc((size_t)5120 * RDIM * 2);
    bf16_t* wqT    = (bf16_t*)alloc((size_t)3072 * DMODEL * 2);
    bf16_t* woT    = (bf16_t*)alloc((size_t)DMODEL * DMODEL * 2);
    float*  kvf    = (float*) alloc((size_t)MROWS * RDIM * 4);
    bf16_t* kvb    = (bf16_t*)alloc((size_t)MROWS * RDIM * 2);
    bf16_t* kvout  = (bf16_t*)alloc((size_t)MROWS * 5120 * 2);
    bf16_t* qfull  = (bf16_t*)alloc((size_t)MROWS * 3072 * 2);
    bf16_t* kpack  = (bf16_t*)alloc((size_t)32 * SEQ * DQK * 2);
    bf16_t* qpack  = (bf16_t*)alloc((size_t)32 * SEQ * DQK * 2);
    bf16_t* vt     = (bf16_t*)alloc((size_t)32 * 128 * SEQ * 2);
    bf16_t* attno  = (bf16_t*)alloc((size_t)MROWS * 2048 * 2);
    float*  costab = (float*) alloc((size_t)SEQ * 32 * 4);
    float*  sintab = (float*) alloc((size_t)SEQ * 32 * 4);

    // prep
    cast_x_kernel<<<(MROWS * DMODEL / 4) / 256, 256, 0, stream>>>(x, xb);
    wtrans_kernel<<<dim3(RDIM / 32, DMODEL / 32), 256, 0, stream>>>(w_kv, wkvT, DMODEL, RDIM);
    wtrans_kernel<<<dim3(3072 / 32, RDIM / 32), 256, 0, stream>>>(w_k, wkvwT, RDIM, 3072);
    wtrans_kernel<<<dim3(2048 / 32, RDIM / 32), 256, 0, stream>>>(w_v, wkvwT + (size_t)3072 * RDIM, RDIM, 2048);
    wtrans_kernel<<<dim3(2048 / 32, DMODEL / 32), 256, 0, stream>>>(w_qn, wqT, DMODEL, 2048);
    wtrans_kernel<<<dim3(1024 / 32, DMODEL / 32), 256, 0, stream>>>(w_qr, wqT + (size_t)2048 * DMODEL, DMODEL, 1024);
    wtrans_kernel<<<dim3(2048 / 32, DMODEL / 32), 256, 0, stream>>>(w_o, woT, DMODEL, 2048);
    rope_table_kernel<<<(SEQ * 32) / 256, 256, 0, stream>>>(freqs, costab, sintab);

    // G1: kv_pre = x @ w_kv   (f32 out for rmsnorm)
    gemm_bt<float><<<dim3(RDIM / 128, MROWS / 128), 256, 0, stream>>>(xb, wkvT, kvf, MROWS, RDIM, DMODEL);
    rmsnorm_kernel<<<MROWS, 256, 0, stream>>>(kvf, g_kv, kvb);
    // G2: [k_full | v] = kv @ [w_k | w_v]
    gemm_bt<bf16_t><<<dim3(5120 / 128, MROWS / 128), 256, 0, stream>>>(kvb, wkvwT, kvout, MROWS, 5120, RDIM);
    // G3: [q_nope | q_rope_pre] = x @ [w_qn | w_qr]
    gemm_bt<bf16_t><<<dim3(3072 / 128, MROWS / 128), 256, 0, stream>>>(xb, wqT, qfull, MROWS, 3072, DMODEL);

    // pack + rope
    pack_q_nope<<<(MROWS * 16 * 16) / 256, 256, 0, stream>>>(qfull, qpack);
    pack_q_rope<<<(MROWS * 16 * 32) / 256, 256, 0, stream>>>(qfull, qpack, costab, sintab);
    pack_k_nope<<<(MROWS * 16 * 16) / 256, 256, 0, stream>>>(kvout, kpack);
    pack_k_rope<<<(MROWS * 16 * 32) / 256, 256, 0, stream>>>(kvout, kpack, costab, sintab);
    pack_v_kernel<<<32 * 32, 256, 0, stream>>>(kvout, vt);

    // attention (1024 blocks: 32 bh x 32 q-tiles, heavy-first)
    attn_kernel<<<1024, 256, 0, stream>>>(qpack, kpack, vt, attno);

    // G4: out = attn_out @ w_o   (f32 out)
    gemm_bt<float><<<dim3(2048 / 128, MROWS / 128), 256, 0, stream>>>(attno, woT, out, MROWS, 2048, DMODEL);
}

// Round 4
// 361.731 us; speedup vs baseline: 1.2668x; 1.2668x over previous
//
#include <hip/hip_runtime.h>

typedef __bf16 bf16_t;
typedef bf16_t bf16x8 __attribute__((ext_vector_type(8)));
typedef bf16_t bf16x4v __attribute__((ext_vector_type(4)));
typedef float f32x4 __attribute__((ext_vector_type(4)));

#define GLDS16(g, l) __builtin_amdgcn_global_load_lds( \
    (const __attribute__((address_space(1))) void*)(g), \
    (__attribute__((address_space(3))) void*)(l), 16, 0, 0)

// Problem constants
#define BB 2
#define SEQ 2048
#define DMODEL 2048
#define RDIM 512
#define NH 16
#define DNOPE 128
#define DROPE 64
#define DVDIM 128
#define MROWS 4096           // BB*SEQ
#define DQK 192              // DNOPE+DROPE

// ---------------- prep kernels ----------------

__global__ __launch_bounds__(256) void cast_x_kernel(const float* __restrict__ x,
                                                     bf16_t* __restrict__ xb) {
    int idx = blockIdx.x * 256 + threadIdx.x;
    float4 v = ((const float4*)x)[idx];
    bf16x4v o;
    o[0] = (bf16_t)v.x; o[1] = (bf16_t)v.y; o[2] = (bf16_t)v.z; o[3] = (bf16_t)v.w;
    ((bf16x4v*)xb)[idx] = o;
}

// W (K x N) f32 -> WT (N x K) bf16, tiled transpose
__global__ __launch_bounds__(256) void wtrans_kernel(const float* __restrict__ W,
                                                     bf16_t* __restrict__ WT,
                                                     int K, int N) {
    __shared__ float t[32][33];
    int n0 = blockIdx.x * 32, k0 = blockIdx.y * 32;
    int tx = threadIdx.x & 31, ty = threadIdx.x >> 5;  // ty 0..7
    #pragma unroll
    for (int i = 0; i < 4; ++i)
        t[ty + i*8][tx] = W[(size_t)(k0 + ty + i*8) * N + n0 + tx];
    __syncthreads();
    #pragma unroll
    for (int i = 0; i < 4; ++i)
        WT[(size_t)(n0 + ty + i*8) * K + k0 + tx] = (bf16_t)t[tx][ty + i*8];
}

__global__ __launch_bounds__(256) void rope_table_kernel(const float* __restrict__ freqs,
                                                         float* __restrict__ costab,
                                                         float* __restrict__ sintab) {
    int idx = blockIdx.x * 256 + threadIdx.x;   // SEQ*32 exact
    float f = freqs[idx];
    costab[idx] = cosf(f);
    sintab[idx] = sinf(f);
}

__global__ __launch_bounds__(256) void rmsnorm_kernel(const float* __restrict__ kvf,
                                                      const float* __restrict__ gkv,
                                                      bf16_t* __restrict__ kvb) {
    int m = blockIdx.x;
    int tid = threadIdx.x;
    const float* rowp = kvf + (size_t)m * RDIM;
    float2 v = *(const float2*)(rowp + tid * 2);
    float ss = v.x * v.x + v.y * v.y;
    #pragma unroll
    for (int d = 1; d < 64; d <<= 1) ss += __shfl_xor(ss, d, 64);
    __shared__ float red[4];
    if ((tid & 63) == 0) red[tid >> 6] = ss;
    __syncthreads();
    float tot = red[0] + red[1] + red[2] + red[3];
    float scale = rsqrtf(tot * (1.0f / RDIM) + 1e-6f);
    bf16_t* orow = kvb + (size_t)m * RDIM;
    orow[tid*2]     = (bf16_t)(v.x * scale * gkv[tid*2]);
    orow[tid*2 + 1] = (bf16_t)(v.y * scale * gkv[tid*2 + 1]);
}

// ---------------- GEMM: C(MxN) = A(MxK) * Bt(NxK)^T, bf16 in, OutT out --------
// 128x128 tile, BK=64, 4 waves (2x2), global_load_lds staging with XOR swizzle.

template<typename OutT>
__global__ __launch_bounds__(256, 2) void gemm_bt(const bf16_t* __restrict__ A,
                                                  const bf16_t* __restrict__ Bt,
                                                  OutT* __restrict__ C,
                                                  int M, int N, int K) {
    __shared__ __align__(16) char ldsA[128 * 128];   // 128 rows x 128B (64 bf16)
    __shared__ __align__(16) char ldsB[128 * 128];
    int tid = threadIdx.x;
    int lane = tid & 63, wave = tid >> 6;
    int n0 = blockIdx.x * 128, m0 = blockIdx.y * 128;
    int wr = wave >> 1, wc = wave & 1;
    int g = lane >> 4, c = lane & 15;
    f32x4 acc[4][4] = {};

    int srow = tid >> 3;         // 0..31: row within 4KB staging slab
    int sch = tid & 7;           // chunk (16B) within 128B row

    int nkt = K >> 6;
    for (int kt = 0; kt < nkt; ++kt) {
        int k0 = kt << 6;
        #pragma unroll
        for (int j = 0; j < 4; ++j) {
            int row = j * 32 + srow;
            int csrc = sch ^ (row & 7);     // pre-swizzled source chunk
            const char* gA = (const char*)(A + (size_t)(m0 + row) * K + k0) + csrc * 16;
            const char* gB = (const char*)(Bt + (size_t)(n0 + row) * K + k0) + csrc * 16;
            char* lA = ldsA + j * 4096 + wave * 1024;
            char* lB = ldsB + j * 4096 + wave * 1024;
            GLDS16(gA, lA);
            GLDS16(gB, lB);
        }
        __syncthreads();
        #pragma unroll
        for (int kk = 0; kk < 2; ++kk) {
            int kb = kk * 64 + g * 16;      // byte offset within row
            bf16x8 aF[4], bF[4];
            #pragma unroll
            for (int m = 0; m < 4; ++m) {
                int row = wr * 64 + m * 16 + c;
                aF[m] = *(const bf16x8*)(ldsA + row * 128 + (kb ^ ((row & 7) << 4)));
            }
            #pragma unroll
            for (int n = 0; n < 4; ++n) {
                int row = wc * 64 + n * 16 + c;
                bF[n] = *(const bf16x8*)(ldsB + row * 128 + (kb ^ ((row & 7) << 4)));
            }
            #pragma unroll
            for (int m = 0; m < 4; ++m)
                #pragma unroll
                for (int n = 0; n < 4; ++n)
                    acc[m][n] = __builtin_amdgcn_mfma_f32_16x16x32_bf16(aF[m], bF[n], acc[m][n], 0, 0, 0);
        }
        __syncthreads();
    }
    // epilogue: C/D layout col=lane&15, row=(lane>>4)*4+i
    #pragma unroll
    for (int m = 0; m < 4; ++m) {
        int grow = m0 + wr * 64 + m * 16 + g * 4;
        #pragma unroll
        for (int n = 0; n < 4; ++n) {
            int gcol = n0 + wc * 64 + n * 16 + c;
            #pragma unroll
            for (int i = 0; i < 4; ++i)
                C[(size_t)(grow + i) * N + gcol] = (OutT)acc[m][n][i];
        }
    }
}

// ---------------- pack / rope kernels ----------------

// qfull [M][3072] -> qpack [BH][S][192] (nope part, d<128)
__global__ __launch_bounds__(256) void pack_q_nope(const bf16_t* __restrict__ qfull,
                                                   bf16_t* __restrict__ qpack) {
    int idx = blockIdx.x * 256 + threadIdx.x;      // M*16*16
    int m = idx >> 8, rest = idx & 255;
    int h = rest >> 4, ch = rest & 15;
    int b = m >> 11, s = m & 2047;
    bf16x8 v = *(const bf16x8*)(qfull + (size_t)m * 3072 + h * 128 + ch * 8);
    *(bf16x8*)(qpack + ((size_t)(b * NH + h) * SEQ + s) * DQK + ch * 8) = v;
}

__global__ __launch_bounds__(256) void pack_q_rope(const bf16_t* __restrict__ qfull,
                                                   bf16_t* __restrict__ qpack,
                                                   const float* __restrict__ costab,
                                                   const float* __restrict__ sintab) {
    int idx = blockIdx.x * 256 + threadIdx.x;      // M*16*32
    int m = idx >> 9, h = (idx >> 5) & 15, j = idx & 31;
    int b = m >> 11, s = m & 2047;
    const bf16_t* src = qfull + (size_t)m * 3072 + 2048 + h * 64 + 2 * j;
    float xr = (float)src[0], xi = (float)src[1];
    float cs = costab[s * 32 + j], sn = sintab[s * 32 + j];
    bf16_t* dst = qpack + ((size_t)(b * NH + h) * SEQ + s) * DQK + DNOPE + 2 * j;
    dst[0] = (bf16_t)(xr * cs - xi * sn);
    dst[1] = (bf16_t)(xr * sn + xi * cs);
}

// kvout [M][5120]: cols 0..3071 = k_full (h*192+d), 3072.. = v (h*128+dv)
__global__ __launch_bounds__(256) void pack_k_nope(const bf16_t* __restrict__ kvout,
                                                   bf16_t* __restrict__ kpack) {
    int idx = blockIdx.x * 256 + threadIdx.x;
    int m = idx >> 8, rest = idx & 255;
    int h = rest >> 4, ch = rest & 15;
    int b = m >> 11, s = m & 2047;
    bf16x8 v = *(const bf16x8*)(kvout + (size_t)m * 5120 + h * DQK + ch * 8);
    *(bf16x8*)(kpack + ((size_t)(b * NH + h) * SEQ + s) * DQK + ch * 8) = v;
}

__global__ __launch_bounds__(256) void pack_k_rope(const bf16_t* __restrict__ kvout,
                                                   bf16_t* __restrict__ kpack,
                                                   const float* __restrict__ costab,
                                                   const float* __restrict__ sintab) {
    int idx = blockIdx.x * 256 + threadIdx.x;
    int m = idx >> 9, h = (idx >> 5) & 15, j = idx & 31;
    int b = m >> 11, s = m & 2047;
    const bf16_t* src = kvout + (size_t)m * 5120 + h * DQK + DNOPE + 2 * j;
    float xr = (float)src[0], xi = (float)src[1];
    float cs = costab[s * 32 + j], sn = sintab[s * 32 + j];
    bf16_t* dst = kpack + ((size_t)(b * NH + h) * SEQ + s) * DQK + DNOPE + 2 * j;
    dst[0] = (bf16_t)(xr * cs - xi * sn);
    dst[1] = (bf16_t)(xr * sn + xi * cs);
}

// v part of kvout -> vt [BH][128][SEQ]  (transposed for PV B-fragments)
__global__ __launch_bounds__(256) void pack_v_kernel(const bf16_t* __restrict__ kvout,
                                                     bf16_t* __restrict__ vt) {
    __shared__ bf16_t t[64][144];
    int blk = blockIdx.x;                 // 32 bh * 32 stiles
    int bh = blk >> 5, st = blk & 31;
    int s0 = st * 64;
    int b = bh >> 4, h = bh & 15;
    int tid = threadIdx.x;
    #pragma unroll
    for (int i = 0; i < 4; ++i) {
        int id = i * 256 + tid;           // 1024: 64 rows x 16 chunks
        int row = id >> 4, ch = id & 15;
        bf16x8 v = *(const bf16x8*)(kvout + (size_t)(b * SEQ + s0 + row) * 5120 + 3072 + h * 128 + ch * 8);
        *(bf16x8*)&t[row][ch * 8] = v;
    }
    __syncthreads();
    #pragma unroll
    for (int i = 0; i < 4; ++i) {
        int id = i * 256 + tid;           // 1024: 128 dv x 8 chunks
        int dv = id >> 3, sc = id & 7;
        bf16x8 v;
        #pragma unroll
        for (int jj = 0; jj < 8; ++jj) v[jj] = t[sc * 8 + jj][dv];
        *(bf16x8*)(vt + ((size_t)bh * 128 + dv) * SEQ + s0 + sc * 8) = v;
    }
}

// ---------------- flash attention v4 ----------------
// Q,K: [BH][S][192] bf16; VT: [BH][128][S] bf16; O: [M][2048] bf16 (col=h*128+dv)
// 1024 blocks (bh x qtile), heavy-first, XCD-aware. 4 waves x 16 q-rows, KV tile 64.
// K AND V staged via global_load_lds (swizzled source, linear dest, swizzled read).
// Row-sum via all-ones V-fragment (accO[8]); defer-max rescale (THR=8).

__global__ __launch_bounds__(256, 3) void attn_kernel(const bf16_t* __restrict__ Q,
                                                      const bf16_t* __restrict__ Kp,
                                                      const bf16_t* __restrict__ VT,
                                                      bf16_t* __restrict__ O) {
    __shared__ __align__(16) char ldsK[64 * 384];     // [64][192] bf16, swizzled content
    __shared__ __align__(16) char ldsV[128 * 128];    // [128 dv][64 s] bf16, swizzled content
    __shared__ __align__(16) char ldsP[4 * 16 * 176]; // per-wave [16][64+24pad] bf16
    int tid = threadIdx.x, lane = tid & 63, wave = tid >> 6;
    int g = lane >> 4, c = lane & 15;

    // XCD-aware mapping: xcd = bid&7 owns 4 heads; qt descending in dispatch order.
    int bid = blockIdx.x;                // 0..1023
    int xcd = bid & 7, idx = bid >> 3;   // idx 0..127
    int bh = xcd * 4 + (idx & 3);        // 0..31
    int qt = 31 - (idx >> 2);            // 31..0
    int b = bh >> 4, h = bh & 15;
    int q0 = qt * 64;
    int nt = qt + 1;

    const bf16_t* Qb = Q + (size_t)bh * SEQ * DQK;
    const bf16_t* Kb = Kp + (size_t)bh * SEQ * DQK;
    const bf16_t* Vb = VT + (size_t)bh * 128 * SEQ;
    char* ldsPw = ldsP + wave * (16 * 176);

    // K staging map: 1536 chunks of 16B; source chunk XORed so linear LDS +
    // swizzled read composes to identity (rule #21).
    int soff[6];
    #pragma unroll
    for (int i2 = 0; i2 < 6; ++i2) {
        int id = i2 * 256 + tid;
        int row = id / 24, ch = id - row * 24;
        soff[i2] = row * 384 + (ch ^ (row & 7)) * 16;
    }
    // V staging map: wave stages rows wave*32..wave*32+31 (4 issues x 8 rows).
    int vrl = lane >> 3;                       // row within 8-row slab
    int vch = (lane & 7) ^ (vrl & 7);          // pre-swizzled source chunk
    const float sc = 0.0721687836f * 1.44269504f;   // 1/sqrt(192) * log2(e)

    bf16x8 vones;
    #pragma unroll
    for (int j = 0; j < 8; ++j) vones[j] = (bf16_t)1.0f;

    bf16x8 qf[6];
    {
        const bf16_t* qrow = Qb + (size_t)(q0 + wave * 16 + c) * DQK + g * 8;
        #pragma unroll
        for (int kk = 0; kk < 6; ++kk) qf[kk] = *(const bf16x8*)(qrow + kk * 32);
    }
    float m_run[4];
    f32x4 accO[9] = {};                        // [8] = running row-sum (ones column)
    #pragma unroll
    for (int i = 0; i < 4; ++i) m_run[i] = -3.0e38f;

    #pragma unroll 1
    for (int t = 0; t < nt; ++t) {
        // stage K tile (24KB) + V tile (16KB) via global_load_lds
        const char* Kt = (const char*)Kb + (size_t)t * 24576;
        #pragma unroll
        for (int i2 = 0; i2 < 6; ++i2)
            GLDS16(Kt + soff[i2], ldsK + i2 * 4096 + wave * 1024);
        const char* Vt = (const char*)Vb + (size_t)t * 128;   // t*64 elems
        #pragma unroll
        for (int j = 0; j < 4; ++j) {
            int row = wave * 32 + j * 8 + vrl;
            GLDS16(Vt + (size_t)row * (SEQ * 2) + vch * 16, ldsV + wave * 4096 + j * 1024);
        }
        __syncthreads();

        // QK^T: per wave 16 q-rows x 64 k
        f32x4 accS[4] = {};
        __builtin_amdgcn_s_setprio(1);
        #pragma unroll
        for (int kk = 0; kk < 6; ++kk) {
            int kb = kk * 64 + g * 16;
            #pragma unroll
            for (int n = 0; n < 4; ++n) {
                int row = n * 16 + c;
                bf16x8 kf = *(const bf16x8*)(ldsK + row * 384 + (kb ^ ((row & 7) << 4)));
                accS[n] = __builtin_amdgcn_mfma_f32_16x16x32_bf16(qf[kk], kf, accS[n], 0, 0, 0);
            }
        }
        __builtin_amdgcn_s_setprio(0);

        // scale + causal mask (only diagonal tile is partial)
        bool diag = (t == nt - 1);
        #pragma unroll
        for (int n = 0; n < 4; ++n)
            #pragma unroll
            for (int i = 0; i < 4; ++i) {
                float v = accS[n][i] * sc;
                if (diag && (n * 16 + c > wave * 16 + g * 4 + i)) v = -1e30f;
                accS[n][i] = v;
            }
        // row max (16 shfl); sum comes free via ones-column MFMA
        float mx[4];
        #pragma unroll
        for (int i = 0; i < 4; ++i) {
            float m2 = fmaxf(fmaxf(accS[0][i], accS[1][i]), fmaxf(accS[2][i], accS[3][i]));
            #pragma unroll
            for (int d = 1; d < 16; d <<= 1) m2 = fmaxf(m2, __shfl_xor(m2, d, 64));
            mx[i] = m2;
        }
        // defer-max: skip rescale while tile max stays within THR of running max
        bool nore = __all((mx[0] <= m_run[0] + 8.f) & (mx[1] <= m_run[1] + 8.f) &
                          (mx[2] <= m_run[2] + 8.f) & (mx[3] <= m_run[3] + 8.f));
        if (nore) {
            #pragma unroll
            for (int i = 0; i < 4; ++i)
                #pragma unroll
                for (int n = 0; n < 4; ++n)
                    accS[n][i] = exp2f(accS[n][i] - m_run[i]);
        } else {
            #pragma unroll
            for (int i = 0; i < 4; ++i) {
                float mnew = fmaxf(m_run[i], mx[i]);
                float alpha = exp2f(m_run[i] - mnew);
                m_run[i] = mnew;
                #pragma unroll
                for (int n = 0; n < 4; ++n)
                    accS[n][i] = exp2f(accS[n][i] - mnew);
                #pragma unroll
                for (int n = 0; n < 9; ++n) accO[n][i] *= alpha;
            }
        }
        // P (C-frag) -> per-wave LDS -> A-frag
        #pragma unroll
        for (int n = 0; n < 4; ++n)
            #pragma unroll
            for (int i = 0; i < 4; ++i)
                *(bf16_t*)(ldsPw + (g * 4 + i) * 176 + (n * 16 + c) * 2) = (bf16_t)accS[n][i];
        bf16x8 pf0 = *(const bf16x8*)(ldsPw + c * 176 + g * 16);
        bf16x8 pf1 = *(const bf16x8*)(ldsPw + c * 176 + 64 + g * 16);

        // PV: V from LDS (swizzled read), plus ones-column for row-sum
        __builtin_amdgcn_s_setprio(1);
        #pragma unroll
        for (int n = 0; n < 8; ++n) {
            int row = n * 16 + c;
            bf16x8 vf0 = *(const bf16x8*)(ldsV + row * 128 + ((g * 16) ^ ((c & 7) << 4)));
            bf16x8 vf1 = *(const bf16x8*)(ldsV + row * 128 + ((64 + g * 16) ^ ((c & 7) << 4)));
            accO[n] = __builtin_amdgcn_mfma_f32_16x16x32_bf16(pf0, vf0, accO[n], 0, 0, 0);
            accO[n] = __builtin_amdgcn_mfma_f32_16x16x32_bf16(pf1, vf1, accO[n], 0, 0, 0);
        }
        accO[8] = __builtin_amdgcn_mfma_f32_16x16x32_bf16(pf0, vones, accO[8], 0, 0, 0);
        accO[8] = __builtin_amdgcn_mfma_f32_16x16x32_bf16(pf1, vones, accO[8], 0, 0, 0);
        __builtin_amdgcn_s_setprio(0);
        __syncthreads();   // all waves done with ldsK/ldsV before next stage
    }
    // write O, normalizing by the ones-column running sum
    float inv_l[4];
    #pragma unroll
    for (int i = 0; i < 4; ++i) inv_l[i] = 1.0f / accO[8][i];
    #pragma unroll
    for (int n = 0; n < 8; ++n) {
        int gcol = h * 128 + n * 16 + c;
        #pragma unroll
        for (int i = 0; i < 4; ++i) {
            int mrow = b * SEQ + q0 + wave * 16 + g * 4 + i;
            O[(size_t)mrow * 2048 + gcol] = (bf16_t)(accO[n][i] * inv_l[i]);
        }
    }
}

// ---------------- launch ----------------

extern "C" void kernel_launch(void* const* d_in, const int* in_sizes, int n_in,
                              void* d_out, int out_size, void* d_ws, size_t ws_size,
                              hipStream_t stream) {
    const float* x     = (const float*)d_in[0];
    const float* freqs = (const float*)d_in[1];
    const float* w_kv  = (const float*)d_in[2];
    const float* g_kv  = (const float*)d_in[3];
    const float* w_k   = (const float*)d_in[4];
    const float* w_v   = (const float*)d_in[5];
    const float* w_qn  = (const float*)d_in[6];
    const float* w_qr  = (const float*)d_in[7];
    const float* w_o   = (const float*)d_in[8];
    float* out = (float*)d_out;

    char* ws = (char*)d_ws;
    size_t off = 0;
    auto alloc = [&](size_t bytes) { char* p = ws + off; off += (bytes + 255) & ~(size_t)255; return p; };
    bf16_t* xb     = (bf16_t*)alloc((size_t)MROWS * DMODEL * 2);
    bf16_t* wkvT   = (bf16_t*)alloc((size_t)RDIM * DMODEL * 2);
    bf16_t* wkvwT  = (bf16_t*)alloc((size_t)5120 * RDIM * 2);
    bf16_t* wqT    = (bf16_t*)alloc((size_t)3072 * DMODEL * 2);
    bf16_t* woT    = (bf16_t*)alloc((size_t)DMODEL * DMODEL * 2);
    float*  kvf    = (float*) alloc((size_t)MROWS * RDIM * 4);
    bf16_t* kvb    = (bf16_t*)alloc((size_t)MROWS * RDIM * 2);
    bf16_t* kvout  = (bf16_t*)alloc((size_t)MROWS * 5120 * 2);
    bf16_t* qfull  = (bf16_t*)alloc((size_t)MROWS * 3072 * 2);
    bf16_t* kpack  = (bf16_t*)alloc((size_t)32 * SEQ * DQK * 2);
    bf16_t* qpack  = (bf16_t*)alloc((size_t)32 * SEQ * DQK * 2);
    bf16_t* vt     = (bf16_t*)alloc((size_t)32 * 128 * SEQ * 2);
    bf16_t* attno  = (bf16_t*)alloc((size_t)MROWS * 2048 * 2);
    float*  costab = (float*) alloc((size_t)SEQ * 32 * 4);
    float*  sintab = (float*) alloc((size_t)SEQ * 32 * 4);

    // prep
    cast_x_kernel<<<(MROWS * DMODEL / 4) / 256, 256, 0, stream>>>(x, xb);
    wtrans_kernel<<<dim3(RDIM / 32, DMODEL / 32), 256, 0, stream>>>(w_kv, wkvT, DMODEL, RDIM);
    wtrans_kernel<<<dim3(3072 / 32, RDIM / 32), 256, 0, stream>>>(w_k, wkvwT, RDIM, 3072);
    wtrans_kernel<<<dim3(2048 / 32, RDIM / 32), 256, 0, stream>>>(w_v, wkvwT + (size_t)3072 * RDIM, RDIM, 2048);
    wtrans_kernel<<<dim3(2048 / 32, DMODEL / 32), 256, 0, stream>>>(w_qn, wqT, DMODEL, 2048);
    wtrans_kernel<<<dim3(1024 / 32, DMODEL / 32), 256, 0, stream>>>(w_qr, wqT + (size_t)2048 * DMODEL, DMODEL, 1024);
    wtrans_kernel<<<dim3(2048 / 32, DMODEL / 32), 256, 0, stream>>>(w_o, woT, DMODEL, 2048);
    rope_table_kernel<<<(SEQ * 32) / 256, 256, 0, stream>>>(freqs, costab, sintab);

    // G1: kv_pre = x @ w_kv   (f32 out for rmsnorm)
    gemm_bt<float><<<dim3(RDIM / 128, MROWS / 128), 256, 0, stream>>>(xb, wkvT, kvf, MROWS, RDIM, DMODEL);
    rmsnorm_kernel<<<MROWS, 256, 0, stream>>>(kvf, g_kv, kvb);
    // G2: [k_full | v] = kv @ [w_k | w_v]
    gemm_bt<bf16_t><<<dim3(5120 / 128, MROWS / 128), 256, 0, stream>>>(kvb, wkvwT, kvout, MROWS, 5120, RDIM);
    // G3: [q_nope | q_rope_pre] = x @ [w_qn | w_qr]
    gemm_bt<bf16_t><<<dim3(3072 / 128, MROWS / 128), 256, 0, stream>>>(xb, wqT, qfull, MROWS, 3072, DMODEL);

    // pack + rope
    pack_q_nope<<<(MROWS * 16 * 16) / 256, 256, 0, stream>>>(qfull, qpack);
    pack_q_rope<<<(MROWS * 16 * 32) / 256, 256, 0, stream>>>(qfull, qpack, costab, sintab);
    pack_k_nope<<<(MROWS * 16 * 16) / 256, 256, 0, stream>>>(kvout, kpack);
    pack_k_rope<<<(MROWS * 16 * 32) / 256, 256, 0, stream>>>(kvout, kpack, costab, sintab);
    pack_v_kernel<<<32 * 32, 256, 0, stream>>>(kvout, vt);

    // attention (1024 blocks: 32 bh x 32 q-tiles, heavy-first)
    attn_kernel<<<1024, 256, 0, stream>>>(qpack, kpack, vt, attno);

    // G4: out = attn_out @ w_o   (f32 out)
    gemm_bt<float><<<dim3(2048 / 128, MROWS / 128), 256, 0, stream>>>(attno, woT, out, MROWS, 2048, DMODEL);
}

// Round 6
// 359.503 us; speedup vs baseline: 1.2747x; 1.0062x over previous
//
#include <hip/hip_runtime.h>

typedef __bf16 bf16_t;
typedef bf16_t bf16x8 __attribute__((ext_vector_type(8)));
typedef bf16_t bf16x4v __attribute__((ext_vector_type(4)));
typedef float f32x4 __attribute__((ext_vector_type(4)));

#define GLDS16(g, l) __builtin_amdgcn_global_load_lds( \
    (const __attribute__((address_space(1))) void*)(g), \
    (__attribute__((address_space(3))) void*)(l), 16, 0, 0)

// Problem constants
#define BB 2
#define SEQ 2048
#define DMODEL 2048
#define RDIM 512
#define NH 16
#define DNOPE 128
#define DROPE 64
#define DVDIM 128
#define MROWS 4096           // BB*SEQ
#define DQK 192              // DNOPE+DROPE

// ---------------- prep kernels ----------------

__global__ __launch_bounds__(256) void cast_x_kernel(const float* __restrict__ x,
                                                     bf16_t* __restrict__ xb) {
    int idx = blockIdx.x * 256 + threadIdx.x;
    float4 v = ((const float4*)x)[idx];
    bf16x4v o;
    o[0] = (bf16_t)v.x; o[1] = (bf16_t)v.y; o[2] = (bf16_t)v.z; o[3] = (bf16_t)v.w;
    ((bf16x4v*)xb)[idx] = o;
}

// W (K x N) f32 -> WT (N x K) bf16, tiled transpose
__global__ __launch_bounds__(256) void wtrans_kernel(const float* __restrict__ W,
                                                     bf16_t* __restrict__ WT,
                                                     int K, int N) {
    __shared__ float t[32][33];
    int n0 = blockIdx.x * 32, k0 = blockIdx.y * 32;
    int tx = threadIdx.x & 31, ty = threadIdx.x >> 5;  // ty 0..7
    #pragma unroll
    for (int i = 0; i < 4; ++i)
        t[ty + i*8][tx] = W[(size_t)(k0 + ty + i*8) * N + n0 + tx];
    __syncthreads();
    #pragma unroll
    for (int i = 0; i < 4; ++i)
        WT[(size_t)(n0 + ty + i*8) * K + k0 + tx] = (bf16_t)t[tx][ty + i*8];
}

__global__ __launch_bounds__(256) void rope_table_kernel(const float* __restrict__ freqs,
                                                         float* __restrict__ costab,
                                                         float* __restrict__ sintab) {
    int idx = blockIdx.x * 256 + threadIdx.x;   // SEQ*32 exact
    float f = freqs[idx];
    costab[idx] = cosf(f);
    sintab[idx] = sinf(f);
}

__global__ __launch_bounds__(256) void rmsnorm_kernel(const float* __restrict__ kvf,
                                                      const float* __restrict__ gkv,
                                                      bf16_t* __restrict__ kvb) {
    int m = blockIdx.x;
    int tid = threadIdx.x;
    const float* rowp = kvf + (size_t)m * RDIM;
    float2 v = *(const float2*)(rowp + tid * 2);
    float ss = v.x * v.x + v.y * v.y;
    #pragma unroll
    for (int d = 1; d < 64; d <<= 1) ss += __shfl_xor(ss, d, 64);
    __shared__ float red[4];
    if ((tid & 63) == 0) red[tid >> 6] = ss;
    __syncthreads();
    float tot = red[0] + red[1] + red[2] + red[3];
    float scale = rsqrtf(tot * (1.0f / RDIM) + 1e-6f);
    bf16_t* orow = kvb + (size_t)m * RDIM;
    orow[tid*2]     = (bf16_t)(v.x * scale * gkv[tid*2]);
    orow[tid*2 + 1] = (bf16_t)(v.y * scale * gkv[tid*2 + 1]);
}

// ---------------- GEMM: C(MxN) = A(MxK) * Bt(NxK)^T, bf16 in, OutT out --------
// 128x128 tile, BK=64, 4 waves (2x2), global_load_lds staging with XOR swizzle.
// EPI: 0 = plain store; 1 = kvout (rope cols n<3072 with n%192>=128);
//      2 = qfull (rope cols n>=2048). Rope pairs live in lanes (c, c^1).

template<typename OutT, int EPI>
__global__ __launch_bounds__(256, 2) void gemm_bt(const bf16_t* __restrict__ A,
                                                  const bf16_t* __restrict__ Bt,
                                                  OutT* __restrict__ C,
                                                  int M, int N, int K,
                                                  const float* __restrict__ costab,
                                                  const float* __restrict__ sintab) {
    __shared__ __align__(16) char ldsA[128 * 128];   // 128 rows x 128B (64 bf16)
    __shared__ __align__(16) char ldsB[128 * 128];
    int tid = threadIdx.x;
    int lane = tid & 63, wave = tid >> 6;
    int n0 = blockIdx.x * 128, m0 = blockIdx.y * 128;
    int wr = wave >> 1, wc = wave & 1;
    int g = lane >> 4, c = lane & 15;
    f32x4 acc[4][4] = {};

    int srow = tid >> 3;         // 0..31: row within 4KB staging slab
    int sch = tid & 7;           // chunk (16B) within 128B row

    int nkt = K >> 6;
    for (int kt = 0; kt < nkt; ++kt) {
        int k0 = kt << 6;
        #pragma unroll
        for (int j = 0; j < 4; ++j) {
            int row = j * 32 + srow;
            int csrc = sch ^ (row & 7);     // pre-swizzled source chunk
            const char* gA = (const char*)(A + (size_t)(m0 + row) * K + k0) + csrc * 16;
            const char* gB = (const char*)(Bt + (size_t)(n0 + row) * K + k0) + csrc * 16;
            char* lA = ldsA + j * 4096 + wave * 1024;
            char* lB = ldsB + j * 4096 + wave * 1024;
            GLDS16(gA, lA);
            GLDS16(gB, lB);
        }
        __syncthreads();
        #pragma unroll
        for (int kk = 0; kk < 2; ++kk) {
            int kb = kk * 64 + g * 16;      // byte offset within row
            bf16x8 aF[4], bF[4];
            #pragma unroll
            for (int m = 0; m < 4; ++m) {
                int row = wr * 64 + m * 16 + c;
                aF[m] = *(const bf16x8*)(ldsA + row * 128 + (kb ^ ((row & 7) << 4)));
            }
            #pragma unroll
            for (int n = 0; n < 4; ++n) {
                int row = wc * 64 + n * 16 + c;
                bF[n] = *(const bf16x8*)(ldsB + row * 128 + (kb ^ ((row & 7) << 4)));
            }
            #pragma unroll
            for (int m = 0; m < 4; ++m)
                #pragma unroll
                for (int n = 0; n < 4; ++n)
                    acc[m][n] = __builtin_amdgcn_mfma_f32_16x16x32_bf16(aF[m], bF[n], acc[m][n], 0, 0, 0);
        }
        __syncthreads();
    }
    // epilogue: C/D layout col=lane&15, row=(lane>>4)*4+i
    #pragma unroll
    for (int m = 0; m < 4; ++m) {
        int grow0 = m0 + wr * 64 + m * 16 + g * 4;
        #pragma unroll
        for (int n = 0; n < 4; ++n) {
            int gcol = n0 + wc * 64 + n * 16 + c;
            bool rope = false;
            int j = 0;
            if (EPI == 1) {
                rope = (gcol < 3072) && ((gcol % 192) >= 128);
                j = ((gcol % 192) - 128) >> 1;
            } else if (EPI == 2) {
                rope = (gcol >= 2048);
                j = ((gcol - 2048) & 63) >> 1;
            }
            if (EPI != 0 && rope) {
                bool even = (c & 1) == 0;
                #pragma unroll
                for (int i = 0; i < 4; ++i) {
                    float v = acc[m][n][i];
                    float pv = __shfl_xor(v, 1, 64);
                    int s = (grow0 + i) & (SEQ - 1);
                    float cs = costab[s * 32 + j], sn = sintab[s * 32 + j];
                    float o = even ? (v * cs - pv * sn) : (pv * sn + v * cs);
                    C[(size_t)(grow0 + i) * N + gcol] = (OutT)o;
                }
            } else {
                #pragma unroll
                for (int i = 0; i < 4; ++i)
                    C[(size_t)(grow0 + i) * N + gcol] = (OutT)acc[m][n][i];
            }
        }
    }
}

// v part of kvout -> vt [BH][128][SEQ]  (transposed for PV B-fragments)
__global__ __launch_bounds__(256) void pack_v_kernel(const bf16_t* __restrict__ kvout,
                                                     bf16_t* __restrict__ vt) {
    __shared__ bf16_t t[64][144];
    int blk = blockIdx.x;                 // 32 bh * 32 stiles
    int bh = blk >> 5, st = blk & 31;
    int s0 = st * 64;
    int b = bh >> 4, h = bh & 15;
    int tid = threadIdx.x;
    #pragma unroll
    for (int i = 0; i < 4; ++i) {
        int id = i * 256 + tid;           // 1024: 64 rows x 16 chunks
        int row = id >> 4, ch = id & 15;
        bf16x8 v = *(const bf16x8*)(kvout + (size_t)(b * SEQ + s0 + row) * 5120 + 3072 + h * 128 + ch * 8);
        *(bf16x8*)&t[row][ch * 8] = v;
    }
    __syncthreads();
    #pragma unroll
    for (int i = 0; i < 4; ++i) {
        int id = i * 256 + tid;           // 1024: 128 dv x 8 chunks
        int dv = id >> 3, sc = id & 7;
        bf16x8 v;
        #pragma unroll
        for (int jj = 0; jj < 8; ++jj) v[jj] = t[sc * 8 + jj][dv];
        *(bf16x8*)(vt + ((size_t)bh * 128 + dv) * SEQ + s0 + sc * 8) = v;
    }
}

// ---------------- flash attention v5 ----------------
// Q direct from qfull [M][3072]; K direct from kvout [M][5120] (h*192 slice);
// VT: [BH][128][S]; O: [M][2048] (col=h*128+dv).
// 512 blocks (bh x 128-row qtile), constant-work pairing, XCD-aware.
// 4 waves; each wave owns TWO 16-row groups (q0+grp*64+wave*16). KV tile 64
// staged once, consumed by both groups. Ones-column row-sum; defer-max.

__global__ __launch_bounds__(256, 2) void attn_kernel(const bf16_t* __restrict__ Qf,
                                                      const bf16_t* __restrict__ KV,
                                                      const bf16_t* __restrict__ VT,
                                                      bf16_t* __restrict__ O) {
    __shared__ __align__(16) char ldsK[64 * 384];     // [64][192] bf16, swizzled content
    __shared__ __align__(16) char ldsV[128 * 128];    // [128 dv][64 s] bf16, swizzled content
    __shared__ __align__(16) char ldsP[4 * 16 * 176]; // per-wave [16][64+24pad] bf16
    int tid = threadIdx.x, lane = tid & 63, wave = tid >> 6;
    int g = lane >> 4, c = lane & 15;

    // XCD-aware mapping; slot<8 -> heavy (qt=15-slot), else light (qt=slot-8):
    // per-CU pair (bid, bid+256) has constant total work.
    int bid = blockIdx.x;                // 0..511
    int xcd = bid & 7, rest = bid >> 3;  // rest 0..63
    int bh = xcd * 4 + (rest & 3);       // 0..31
    int slot = rest >> 2;                // 0..15
    int qt = (slot < 8) ? (15 - slot) : (slot - 8);
    int b = bh >> 4, h = bh & 15;
    int q0 = qt * 128;
    int nt = 2 * qt + 2;

    const bf16_t* Kb = KV + (size_t)b * SEQ * 5120 + h * DQK;   // + s*5120
    const bf16_t* Vb = VT + (size_t)bh * 128 * SEQ;
    char* ldsPw = ldsP + wave * (16 * 176);

    // K staging map: 1536 chunks of 16B; row stride 5120 elems (10240 B).
    // Source chunk XORed so linear LDS + swizzled read composes to identity.
    size_t soff[6];
    #pragma unroll
    for (int i2 = 0; i2 < 6; ++i2) {
        int id = i2 * 256 + tid;
        int row = id / 24, ch = id - row * 24;
        soff[i2] = (size_t)row * 10240 + (ch ^ (row & 7)) * 16;
    }
    // V staging map: wave stages rows wave*32..wave*32+31 (4 issues x 8 rows).
    int vrl = lane >> 3;                       // row within 8-row slab
    int vch = (lane & 7) ^ (vrl & 7);          // pre-swizzled source chunk
    const float sc = 0.0721687836f * 1.44269504f;   // 1/sqrt(192) * log2(e)

    bf16x8 vones;
    #pragma unroll
    for (int j = 0; j < 8; ++j) vones[j] = (bf16_t)1.0f;

    // Q fragments for both 16-row groups (rows q0 + grp*64 + wave*16 + c);
    // A-frag: lane (g,c) holds Q[row=c][k = kk*32 + g*8 + 0..7]
    bf16x8 qf[2][6];
    #pragma unroll
    for (int grp = 0; grp < 2; ++grp) {
        int qrow = q0 + grp * 64 + wave * 16 + c;
        const bf16_t* qn = Qf + (size_t)(b * SEQ + qrow) * 3072 + h * DNOPE + g * 8;
        #pragma unroll
        for (int kk = 0; kk < 4; ++kk) qf[grp][kk] = *(const bf16x8*)(qn + kk * 32);
        const bf16_t* qr = Qf + (size_t)(b * SEQ + qrow) * 3072 + 2048 + h * DROPE + g * 8;
        qf[grp][4] = *(const bf16x8*)(qr);
        qf[grp][5] = *(const bf16x8*)(qr + 32);
    }
    float m_run[2][4];
    f32x4 accO[2][9] = {};                     // [.][8] = running row-sum
    #pragma unroll
    for (int grp = 0; grp < 2; ++grp)
        #pragma unroll
        for (int i = 0; i < 4; ++i) m_run[grp][i] = -3.0e38f;

    #pragma unroll 1
    for (int t = 0; t < nt; ++t) {
        // stage K tile (24KB) + V tile (16KB) via global_load_lds
        const char* Kt = (const char*)(Kb + (size_t)t * 64 * 5120);
        #pragma unroll
        for (int i2 = 0; i2 < 6; ++i2)
            GLDS16(Kt + soff[i2], ldsK + i2 * 4096 + wave * 1024);
        const char* Vt = (const char*)Vb + (size_t)t * 128;   // t*64 elems
        #pragma unroll
        for (int j = 0; j < 4; ++j) {
            int row = wave * 32 + j * 8 + vrl;
            GLDS16(Vt + (size_t)row * (SEQ * 2) + vch * 16, ldsV + wave * 4096 + j * 1024);
        }
        __syncthreads();

        #pragma unroll
        for (int grp = 0; grp < 2; ++grp) {
            if (grp == 0 && t == nt - 1) continue;   // tile beyond grp0's diagonal
            bool diag = (t == nt - 2 + grp);

            // QK^T: 16 q-rows x 64 k
            f32x4 accS[4] = {};
            __builtin_amdgcn_s_setprio(1);
            #pragma unroll
            for (int kk = 0; kk < 6; ++kk) {
                int kb = kk * 64 + g * 16;
                #pragma unroll
                for (int n = 0; n < 4; ++n) {
                    int row = n * 16 + c;
                    bf16x8 kf = *(const bf16x8*)(ldsK + row * 384 + (kb ^ ((row & 7) << 4)));
                    accS[n] = __builtin_amdgcn_mfma_f32_16x16x32_bf16(qf[grp][kk], kf, accS[n], 0, 0, 0);
                }
            }
            __builtin_amdgcn_s_setprio(0);

            // scale + causal mask (diag tile aligns with this grp's 64 rows)
            #pragma unroll
            for (int n = 0; n < 4; ++n)
                #pragma unroll
                for (int i = 0; i < 4; ++i) {
                    float v = accS[n][i] * sc;
                    if (diag && (n * 16 + c > wave * 16 + g * 4 + i)) v = -1e30f;
                    accS[n][i] = v;
                }
            // row max; sum comes free via ones-column MFMA
            float mx[4];
            #pragma unroll
            for (int i = 0; i < 4; ++i) {
                float m2 = fmaxf(fmaxf(accS[0][i], accS[1][i]), fmaxf(accS[2][i], accS[3][i]));
                #pragma unroll
                for (int d = 1; d < 16; d <<= 1) m2 = fmaxf(m2, __shfl_xor(m2, d, 64));
                mx[i] = m2;
            }
            bool nore = __all((mx[0] <= m_run[grp][0] + 8.f) & (mx[1] <= m_run[grp][1] + 8.f) &
                              (mx[2] <= m_run[grp][2] + 8.f) & (mx[3] <= m_run[grp][3] + 8.f));
            if (nore) {
                #pragma unroll
                for (int i = 0; i < 4; ++i)
                    #pragma unroll
                    for (int n = 0; n < 4; ++n)
                        accS[n][i] = exp2f(accS[n][i] - m_run[grp][i]);
            } else {
                #pragma unroll
                for (int i = 0; i < 4; ++i) {
                    float mnew = fmaxf(m_run[grp][i], mx[i]);
                    float alpha = exp2f(m_run[grp][i] - mnew);
                    m_run[grp][i] = mnew;
                    #pragma unroll
                    for (int n = 0; n < 4; ++n)
                        accS[n][i] = exp2f(accS[n][i] - mnew);
                    #pragma unroll
                    for (int n = 0; n < 9; ++n) accO[grp][n][i] *= alpha;
                }
            }
            // P (C-frag) -> per-wave LDS -> A-frag
            #pragma unroll
            for (int n = 0; n < 4; ++n)
                #pragma unroll
                for (int i = 0; i < 4; ++i)
                    *(bf16_t*)(ldsPw + (g * 4 + i) * 176 + (n * 16 + c) * 2) = (bf16_t)accS[n][i];
            bf16x8 pf0 = *(const bf16x8*)(ldsPw + c * 176 + g * 16);
            bf16x8 pf1 = *(const bf16x8*)(ldsPw + c * 176 + 64 + g * 16);

            // PV: V from LDS (swizzled read), plus ones-column for row-sum
            __builtin_amdgcn_s_setprio(1);
            #pragma unroll
            for (int n = 0; n < 8; ++n) {
                int row = n * 16 + c;
                bf16x8 vf0 = *(const bf16x8*)(ldsV + row * 128 + ((g * 16) ^ ((c & 7) << 4)));
                bf16x8 vf1 = *(const bf16x8*)(ldsV + row * 128 + ((64 + g * 16) ^ ((c & 7) << 4)));
                accO[grp][n] = __builtin_amdgcn_mfma_f32_16x16x32_bf16(pf0, vf0, accO[grp][n], 0, 0, 0);
                accO[grp][n] = __builtin_amdgcn_mfma_f32_16x16x32_bf16(pf1, vf1, accO[grp][n], 0, 0, 0);
            }
            accO[grp][8] = __builtin_amdgcn_mfma_f32_16x16x32_bf16(pf0, vones, accO[grp][8], 0, 0, 0);
            accO[grp][8] = __builtin_amdgcn_mfma_f32_16x16x32_bf16(pf1, vones, accO[grp][8], 0, 0, 0);
            __builtin_amdgcn_s_setprio(0);
        }
        __syncthreads();   // all waves done with ldsK/ldsV before next stage
    }
    // write O, normalizing by the ones-column running sum
    #pragma unroll
    for (int grp = 0; grp < 2; ++grp) {
        float inv_l[4];
        #pragma unroll
        for (int i = 0; i < 4; ++i) inv_l[i] = 1.0f / accO[grp][8][i];
        #pragma unroll
        for (int n = 0; n < 8; ++n) {
            int gcol = h * 128 + n * 16 + c;
            #pragma unroll
            for (int i = 0; i < 4; ++i) {
                int mrow = b * SEQ + q0 + grp * 64 + wave * 16 + g * 4 + i;
                O[(size_t)mrow * 2048 + gcol] = (bf16_t)(accO[grp][n][i] * inv_l[i]);
            }
        }
    }
}

// ---------------- launch ----------------

extern "C" void kernel_launch(void* const* d_in, const int* in_sizes, int n_in,
                              void* d_out, int out_size, void* d_ws, size_t ws_size,
                              hipStream_t stream) {
    const float* x     = (const float*)d_in[0];
    const float* freqs = (const float*)d_in[1];
    const float* w_kv  = (const float*)d_in[2];
    const float* g_kv  = (const float*)d_in[3];
    const float* w_k   = (const float*)d_in[4];
    const float* w_v   = (const float*)d_in[5];
    const float* w_qn  = (const float*)d_in[6];
    const float* w_qr  = (const float*)d_in[7];
    const float* w_o   = (const float*)d_in[8];
    float* out = (float*)d_out;

    char* ws = (char*)d_ws;
    size_t off = 0;
    auto alloc = [&](size_t bytes) { char* p = ws + off; off += (bytes + 255) & ~(size_t)255; return p; };
    bf16_t* xb     = (bf16_t*)alloc((size_t)MROWS * DMODEL * 2);
    bf16_t* wkvT   = (bf16_t*)alloc((size_t)RDIM * DMODEL * 2);
    bf16_t* wkvwT  = (bf16_t*)alloc((size_t)5120 * RDIM * 2);
    bf16_t* wqT    = (bf16_t*)alloc((size_t)3072 * DMODEL * 2);
    bf16_t* woT    = (bf16_t*)alloc((size_t)DMODEL * DMODEL * 2);
    float*  kvf    = (float*) alloc((size_t)MROWS * RDIM * 4);
    bf16_t* kvb    = (bf16_t*)alloc((size_t)MROWS * RDIM * 2);
    bf16_t* kvout  = (bf16_t*)alloc((size_t)MROWS * 5120 * 2);
    bf16_t* qfull  = (bf16_t*)alloc((size_t)MROWS * 3072 * 2);
    bf16_t* vt     = (bf16_t*)alloc((size_t)32 * 128 * SEQ * 2);
    bf16_t* attno  = (bf16_t*)alloc((size_t)MROWS * 2048 * 2);
    float*  costab = (float*) alloc((size_t)SEQ * 32 * 4);
    float*  sintab = (float*) alloc((size_t)SEQ * 32 * 4);

    // prep
    cast_x_kernel<<<(MROWS * DMODEL / 4) / 256, 256, 0, stream>>>(x, xb);
    wtrans_kernel<<<dim3(RDIM / 32, DMODEL / 32), 256, 0, stream>>>(w_kv, wkvT, DMODEL, RDIM);
    wtrans_kernel<<<dim3(3072 / 32, RDIM / 32), 256, 0, stream>>>(w_k, wkvwT, RDIM, 3072);
    wtrans_kernel<<<dim3(2048 / 32, RDIM / 32), 256, 0, stream>>>(w_v, wkvwT + (size_t)3072 * RDIM, RDIM, 2048);
    wtrans_kernel<<<dim3(2048 / 32, DMODEL / 32), 256, 0, stream>>>(w_qn, wqT, DMODEL, 2048);
    wtrans_kernel<<<dim3(1024 / 32, DMODEL / 32), 256, 0, stream>>>(w_qr, wqT + (size_t)2048 * DMODEL, DMODEL, 1024);
    wtrans_kernel<<<dim3(2048 / 32, DMODEL / 32), 256, 0, stream>>>(w_o, woT, DMODEL, 2048);
    rope_table_kernel<<<(SEQ * 32) / 256, 256, 0, stream>>>(freqs, costab, sintab);

    // G1: kv_pre = x @ w_kv   (f32 out for rmsnorm)
    gemm_bt<float, 0><<<dim3(RDIM / 128, MROWS / 128), 256, 0, stream>>>(xb, wkvT, kvf, MROWS, RDIM, DMODEL, nullptr, nullptr);
    rmsnorm_kernel<<<MROWS, 256, 0, stream>>>(kvf, g_kv, kvb);
    // G2: [k_full | v] = kv @ [w_k | w_v], rope fused on k-rope cols
    gemm_bt<bf16_t, 1><<<dim3(5120 / 128, MROWS / 128), 256, 0, stream>>>(kvb, wkvwT, kvout, MROWS, 5120, RDIM, costab, sintab);
    // G3: [q_nope | q_rope] = x @ [w_qn | w_qr], rope fused on cols >= 2048
    gemm_bt<bf16_t, 2><<<dim3(3072 / 128, MROWS / 128), 256, 0, stream>>>(xb, wqT, qfull, MROWS, 3072, DMODEL, costab, sintab);

    // v transpose only (k/q consumed in native layouts)
    pack_v_kernel<<<32 * 32, 256, 0, stream>>>(kvout, vt);

    // attention (512 blocks: 32 bh x 16 q-tiles of 128 rows)
    attn_kernel<<<512, 256, 0, stream>>>(qfull, kvout, vt, attno);

    // G4: out = attn_out @ w_o   (f32 out)
    gemm_bt<float, 0><<<dim3(2048 / 128, MROWS / 128), 256, 0, stream>>>(attno, woT, out, MROWS, 2048, DMODEL, nullptr, nullptr);
}

// Round 7
// 358.680 us; speedup vs baseline: 1.2776x; 1.0023x over previous
//
#include <hip/hip_runtime.h>

typedef __bf16 bf16_t;
typedef bf16_t bf16x8 __attribute__((ext_vector_type(8)));
typedef bf16_t bf16x4v __attribute__((ext_vector_type(4)));
typedef float f32x4 __attribute__((ext_vector_type(4)));

#define GLDS16(g, l) __builtin_amdgcn_global_load_lds( \
    (const __attribute__((address_space(1))) void*)(g), \
    (__attribute__((address_space(3))) void*)(l), 16, 0, 0)

// Problem constants
#define BB 2
#define SEQ 2048
#define DMODEL 2048
#define RDIM 512
#define NH 16
#define DNOPE 128
#define DROPE 64
#define DVDIM 128
#define MROWS 4096           // BB*SEQ
#define DQK 192              // DNOPE+DROPE

// ---------------- prep kernels ----------------

__global__ __launch_bounds__(256) void cast_x_kernel(const float* __restrict__ x,
                                                     bf16_t* __restrict__ xb) {
    int idx = blockIdx.x * 256 + threadIdx.x;
    float4 v = ((const float4*)x)[idx];
    bf16x4v o;
    o[0] = (bf16_t)v.x; o[1] = (bf16_t)v.y; o[2] = (bf16_t)v.z; o[3] = (bf16_t)v.w;
    ((bf16x4v*)xb)[idx] = o;
}

// W (K x N) f32 -> WT (N x K) bf16, tiled transpose
__global__ __launch_bounds__(256) void wtrans_kernel(const float* __restrict__ W,
                                                     bf16_t* __restrict__ WT,
                                                     int K, int N) {
    __shared__ float t[32][33];
    int n0 = blockIdx.x * 32, k0 = blockIdx.y * 32;
    int tx = threadIdx.x & 31, ty = threadIdx.x >> 5;  // ty 0..7
    #pragma unroll
    for (int i = 0; i < 4; ++i)
        t[ty + i*8][tx] = W[(size_t)(k0 + ty + i*8) * N + n0 + tx];
    __syncthreads();
    #pragma unroll
    for (int i = 0; i < 4; ++i)
        WT[(size_t)(n0 + ty + i*8) * K + k0 + tx] = (bf16_t)t[tx][ty + i*8];
}

__global__ __launch_bounds__(256) void rope_table_kernel(const float* __restrict__ freqs,
                                                         float* __restrict__ costab,
                                                         float* __restrict__ sintab) {
    int idx = blockIdx.x * 256 + threadIdx.x;   // SEQ*32 exact
    float f = freqs[idx];
    costab[idx] = cosf(f);
    sintab[idx] = sinf(f);
}

__global__ __launch_bounds__(256) void rmsnorm_kernel(const float* __restrict__ kvf,
                                                      const float* __restrict__ gkv,
                                                      bf16_t* __restrict__ kvb) {
    int m = blockIdx.x;
    int tid = threadIdx.x;
    const float* rowp = kvf + (size_t)m * RDIM;
    float2 v = *(const float2*)(rowp + tid * 2);
    float ss = v.x * v.x + v.y * v.y;
    #pragma unroll
    for (int d = 1; d < 64; d <<= 1) ss += __shfl_xor(ss, d, 64);
    __shared__ float red[4];
    if ((tid & 63) == 0) red[tid >> 6] = ss;
    __syncthreads();
    float tot = red[0] + red[1] + red[2] + red[3];
    float scale = rsqrtf(tot * (1.0f / RDIM) + 1e-6f);
    bf16_t* orow = kvb + (size_t)m * RDIM;
    orow[tid*2]     = (bf16_t)(v.x * scale * gkv[tid*2]);
    orow[tid*2 + 1] = (bf16_t)(v.y * scale * gkv[tid*2 + 1]);
}

// ---------------- GEMM: C(MxN) = A(MxK) * Bt(NxK)^T, bf16 in, OutT out --------
// 128x128 tile, BK=64, 4 waves (2x2), global_load_lds staging with XOR swizzle.
// EPI: 0 = plain store; 1 = kvout (rope cols n<3072 with n%192>=128);
//      2 = qfull (rope cols n>=2048). Rope pairs live in lanes (c, c^1).

template<typename OutT, int EPI>
__global__ __launch_bounds__(256, 2) void gemm_bt(const bf16_t* __restrict__ A,
                                                  const bf16_t* __restrict__ Bt,
                                                  OutT* __restrict__ C,
                                                  int M, int N, int K,
                                                  const float* __restrict__ costab,
                                                  const float* __restrict__ sintab) {
    __shared__ __align__(16) char ldsA[128 * 128];   // 128 rows x 128B (64 bf16)
    __shared__ __align__(16) char ldsB[128 * 128];
    int tid = threadIdx.x;
    int lane = tid & 63, wave = tid >> 6;
    int n0 = blockIdx.x * 128, m0 = blockIdx.y * 128;
    int wr = wave >> 1, wc = wave & 1;
    int g = lane >> 4, c = lane & 15;
    f32x4 acc[4][4] = {};

    int srow = tid >> 3;         // 0..31: row within 4KB staging slab
    int sch = tid & 7;           // chunk (16B) within 128B row

    int nkt = K >> 6;
    for (int kt = 0; kt < nkt; ++kt) {
        int k0 = kt << 6;
        #pragma unroll
        for (int j = 0; j < 4; ++j) {
            int row = j * 32 + srow;
            int csrc = sch ^ (row & 7);     // pre-swizzled source chunk
            const char* gA = (const char*)(A + (size_t)(m0 + row) * K + k0) + csrc * 16;
            const char* gB = (const char*)(Bt + (size_t)(n0 + row) * K + k0) + csrc * 16;
            char* lA = ldsA + j * 4096 + wave * 1024;
            char* lB = ldsB + j * 4096 + wave * 1024;
            GLDS16(gA, lA);
            GLDS16(gB, lB);
        }
        __syncthreads();
        #pragma unroll
        for (int kk = 0; kk < 2; ++kk) {
            int kb = kk * 64 + g * 16;      // byte offset within row
            bf16x8 aF[4], bF[4];
            #pragma unroll
            for (int m = 0; m < 4; ++m) {
                int row = wr * 64 + m * 16 + c;
                aF[m] = *(const bf16x8*)(ldsA + row * 128 + (kb ^ ((row & 7) << 4)));
            }
            #pragma unroll
            for (int n = 0; n < 4; ++n) {
                int row = wc * 64 + n * 16 + c;
                bF[n] = *(const bf16x8*)(ldsB + row * 128 + (kb ^ ((row & 7) << 4)));
            }
            #pragma unroll
            for (int m = 0; m < 4; ++m)
                #pragma unroll
                for (int n = 0; n < 4; ++n)
                    acc[m][n] = __builtin_amdgcn_mfma_f32_16x16x32_bf16(aF[m], bF[n], acc[m][n], 0, 0, 0);
        }
        __syncthreads();
    }
    // epilogue: C/D layout col=lane&15, row=(lane>>4)*4+i
    #pragma unroll
    for (int m = 0; m < 4; ++m) {
        int grow0 = m0 + wr * 64 + m * 16 + g * 4;
        #pragma unroll
        for (int n = 0; n < 4; ++n) {
            int gcol = n0 + wc * 64 + n * 16 + c;
            bool rope = false;
            int j = 0;
            if (EPI == 1) {
                rope = (gcol < 3072) && ((gcol % 192) >= 128);
                j = ((gcol % 192) - 128) >> 1;
            } else if (EPI == 2) {
                rope = (gcol >= 2048);
                j = ((gcol - 2048) & 63) >> 1;
            }
            if (EPI != 0 && rope) {
                bool even = (c & 1) == 0;
                #pragma unroll
                for (int i = 0; i < 4; ++i) {
                    float v = acc[m][n][i];
                    float pv = __shfl_xor(v, 1, 64);
                    int s = (grow0 + i) & (SEQ - 1);
                    float cs = costab[s * 32 + j], sn = sintab[s * 32 + j];
                    float o = even ? (v * cs - pv * sn) : (pv * sn + v * cs);
                    C[(size_t)(grow0 + i) * N + gcol] = (OutT)o;
                }
            } else {
                #pragma unroll
                for (int i = 0; i < 4; ++i)
                    C[(size_t)(grow0 + i) * N + gcol] = (OutT)acc[m][n][i];
            }
        }
    }
}

// v part of kvout -> vt [BH][128][SEQ]  (transposed for PV B-fragments)
__global__ __launch_bounds__(256) void pack_v_kernel(const bf16_t* __restrict__ kvout,
                                                     bf16_t* __restrict__ vt) {
    __shared__ bf16_t t[64][144];
    int blk = blockIdx.x;                 // 32 bh * 32 stiles
    int bh = blk >> 5, st = blk & 31;
    int s0 = st * 64;
    int b = bh >> 4, h = bh & 15;
    int tid = threadIdx.x;
    #pragma unroll
    for (int i = 0; i < 4; ++i) {
        int id = i * 256 + tid;           // 1024: 64 rows x 16 chunks
        int row = id >> 4, ch = id & 15;
        bf16x8 v = *(const bf16x8*)(kvout + (size_t)(b * SEQ + s0 + row) * 5120 + 3072 + h * 128 + ch * 8);
        *(bf16x8*)&t[row][ch * 8] = v;
    }
    __syncthreads();
    #pragma unroll
    for (int i = 0; i < 4; ++i) {
        int id = i * 256 + tid;           // 1024: 128 dv x 8 chunks
        int dv = id >> 3, sc = id & 7;
        bf16x8 v;
        #pragma unroll
        for (int jj = 0; jj < 8; ++jj) v[jj] = t[sc * 8 + jj][dv];
        *(bf16x8*)(vt + ((size_t)bh * 128 + dv) * SEQ + s0 + sc * 8) = v;
    }
}

// ---------------- flash attention v5 ----------------
// Q direct from qfull [M][3072]; K direct from kvout [M][5120] (h*192 slice);
// VT: [BH][128][S]; O: [M][2048] (col=h*128+dv).
// 512 blocks (bh x 128-row qtile), constant-work pairing, XCD-aware.
// 4 waves; each wave owns TWO 16-row groups (q0+grp*64+wave*16). KV tile 64
// staged once, consumed by both groups. Ones-column row-sum; defer-max.

__global__ __launch_bounds__(256, 2) void attn_kernel(const bf16_t* __restrict__ Qf,
                                                      const bf16_t* __restrict__ KV,
                                                      const bf16_t* __restrict__ VT,
                                                      bf16_t* __restrict__ O) {
    __shared__ __align__(16) char ldsK[64 * 384];     // [64][192] bf16, swizzled content
    __shared__ __align__(16) char ldsV[128 * 128];    // [128 dv][64 s] bf16, swizzled content
    __shared__ __align__(16) char ldsP[4 * 16 * 176]; // per-wave [16][64+24pad] bf16
    int tid = threadIdx.x, lane = tid & 63, wave = tid >> 6;
    int g = lane >> 4, c = lane & 15;

    // XCD-aware mapping; slot<8 -> heavy (qt=15-slot), else light (qt=slot-8):
    // per-CU pair (bid, bid+256) has constant total work.
    int bid = blockIdx.x;                // 0..511
    int xcd = bid & 7, rest = bid >> 3;  // rest 0..63
    int bh = xcd * 4 + (rest & 3);       // 0..31
    int slot = rest >> 2;                // 0..15
    int qt = (slot < 8) ? (15 - slot) : (slot - 8);
    int b = bh >> 4, h = bh & 15;
    int q0 = qt * 128;
    int nt = 2 * qt + 2;

    const bf16_t* Kb = KV + (size_t)b * SEQ * 5120 + h * DQK;   // + s*5120
    const bf16_t* Vb = VT + (size_t)bh * 128 * SEQ;
    char* ldsPw = ldsP + wave * (16 * 176);

    // K staging map: 1536 chunks of 16B; row stride 5120 elems (10240 B).
    // Source chunk XORed so linear LDS + swizzled read composes to identity.
    size_t soff[6];
    #pragma unroll
    for (int i2 = 0; i2 < 6; ++i2) {
        int id = i2 * 256 + tid;
        int row = id / 24, ch = id - row * 24;
        soff[i2] = (size_t)row * 10240 + (ch ^ (row & 7)) * 16;
    }
    // V staging map: wave stages rows wave*32..wave*32+31 (4 issues x 8 rows).
    int vrl = lane >> 3;                       // row within 8-row slab
    int vch = (lane & 7) ^ (vrl & 7);          // pre-swizzled source chunk
    const float sc = 0.0721687836f * 1.44269504f;   // 1/sqrt(192) * log2(e)

    bf16x8 vones;
    #pragma unroll
    for (int j = 0; j < 8; ++j) vones[j] = (bf16_t)1.0f;

    // Q fragments for both 16-row groups (rows q0 + grp*64 + wave*16 + c);
    // A-frag: lane (g,c) holds Q[row=c][k = kk*32 + g*8 + 0..7]
    bf16x8 qf[2][6];
    #pragma unroll
    for (int grp = 0; grp < 2; ++grp) {
        int qrow = q0 + grp * 64 + wave * 16 + c;
        const bf16_t* qn = Qf + (size_t)(b * SEQ + qrow) * 3072 + h * DNOPE + g * 8;
        #pragma unroll
        for (int kk = 0; kk < 4; ++kk) qf[grp][kk] = *(const bf16x8*)(qn + kk * 32);
        const bf16_t* qr = Qf + (size_t)(b * SEQ + qrow) * 3072 + 2048 + h * DROPE + g * 8;
        qf[grp][4] = *(const bf16x8*)(qr);
        qf[grp][5] = *(const bf16x8*)(qr + 32);
    }
    float m_run[2][4];
    f32x4 accO[2][9] = {};                     // [.][8] = running row-sum
    #pragma unroll
    for (int grp = 0; grp < 2; ++grp)
        #pragma unroll
        for (int i = 0; i < 4; ++i) m_run[grp][i] = -3.0e38f;

    #pragma unroll 1
    for (int t = 0; t < nt; ++t) {
        // stage K tile (24KB) + V tile (16KB) via global_load_lds
        const char* Kt = (const char*)(Kb + (size_t)t * 64 * 5120);
        #pragma unroll
        for (int i2 = 0; i2 < 6; ++i2)
            GLDS16(Kt + soff[i2], ldsK + i2 * 4096 + wave * 1024);
        const char* Vt = (const char*)Vb + (size_t)t * 128;   // t*64 elems
        #pragma unroll
        for (int j = 0; j < 4; ++j) {
            int row = wave * 32 + j * 8 + vrl;
            GLDS16(Vt + (size_t)row * (SEQ * 2) + vch * 16, ldsV + wave * 4096 + j * 1024);
        }
        __syncthreads();

        #pragma unroll
        for (int grp = 0; grp < 2; ++grp) {
            if (grp == 0 && t == nt - 1) continue;   // tile beyond grp0's diagonal
            bool diag = (t == nt - 2 + grp);

            // QK^T: 16 q-rows x 64 k
            f32x4 accS[4] = {};
            __builtin_amdgcn_s_setprio(1);
            #pragma unroll
            for (int kk = 0; kk < 6; ++kk) {
                int kb = kk * 64 + g * 16;
                #pragma unroll
                for (int n = 0; n < 4; ++n) {
                    int row = n * 16 + c;
                    bf16x8 kf = *(const bf16x8*)(ldsK + row * 384 + (kb ^ ((row & 7) << 4)));
                    accS[n] = __builtin_amdgcn_mfma_f32_16x16x32_bf16(qf[grp][kk], kf, accS[n], 0, 0, 0);
                }
            }
            __builtin_amdgcn_s_setprio(0);

            // scale + causal mask (diag tile aligns with this grp's 64 rows)
            #pragma unroll
            for (int n = 0; n < 4; ++n)
                #pragma unroll
                for (int i = 0; i < 4; ++i) {
                    float v = accS[n][i] * sc;
                    if (diag && (n * 16 + c > wave * 16 + g * 4 + i)) v = -1e30f;
                    accS[n][i] = v;
                }
            // row max; sum comes free via ones-column MFMA
            float mx[4];
            #pragma unroll
            for (int i = 0; i < 4; ++i) {
                float m2 = fmaxf(fmaxf(accS[0][i], accS[1][i]), fmaxf(accS[2][i], accS[3][i]));
                #pragma unroll
                for (int d = 1; d < 16; d <<= 1) m2 = fmaxf(m2, __shfl_xor(m2, d, 64));
                mx[i] = m2;
            }
            bool nore = __all((mx[0] <= m_run[grp][0] + 8.f) & (mx[1] <= m_run[grp][1] + 8.f) &
                              (mx[2] <= m_run[grp][2] + 8.f) & (mx[3] <= m_run[grp][3] + 8.f));
            if (nore) {
                #pragma unroll
                for (int i = 0; i < 4; ++i)
                    #pragma unroll
                    for (int n = 0; n < 4; ++n)
                        accS[n][i] = exp2f(accS[n][i] - m_run[grp][i]);
            } else {
                #pragma unroll
                for (int i = 0; i < 4; ++i) {
                    float mnew = fmaxf(m_run[grp][i], mx[i]);
                    float alpha = exp2f(m_run[grp][i] - mnew);
                    m_run[grp][i] = mnew;
                    #pragma unroll
                    for (int n = 0; n < 4; ++n)
                        accS[n][i] = exp2f(accS[n][i] - mnew);
                    #pragma unroll
                    for (int n = 0; n < 9; ++n) accO[grp][n][i] *= alpha;
                }
            }
            // P (C-frag) -> per-wave LDS -> A-frag
            #pragma unroll
            for (int n = 0; n < 4; ++n)
                #pragma unroll
                for (int i = 0; i < 4; ++i)
                    *(bf16_t*)(ldsPw + (g * 4 + i) * 176 + (n * 16 + c) * 2) = (bf16_t)accS[n][i];
            bf16x8 pf0 = *(const bf16x8*)(ldsPw + c * 176 + g * 16);
            bf16x8 pf1 = *(const bf16x8*)(ldsPw + c * 176 + 64 + g * 16);

            // PV: V from LDS (swizzled read), plus ones-column for row-sum
            __builtin_amdgcn_s_setprio(1);
            #pragma unroll
            for (int n = 0; n < 8; ++n) {
                int row = n * 16 + c;
                bf16x8 vf0 = *(const bf16x8*)(ldsV + row * 128 + ((g * 16) ^ ((c & 7) << 4)));
                bf16x8 vf1 = *(const bf16x8*)(ldsV + row * 128 + ((64 + g * 16) ^ ((c & 7) << 4)));
                accO[grp][n] = __builtin_amdgcn_mfma_f32_16x16x32_bf16(pf0, vf0, accO[grp][n], 0, 0, 0);
                accO[grp][n] = __builtin_amdgcn_mfma_f32_16x16x32_bf16(pf1, vf1, accO[grp][n], 0, 0, 0);
            }
            accO[grp][8] = __builtin_amdgcn_mfma_f32_16x16x32_bf16(pf0, vones, accO[grp][8], 0, 0, 0);
            accO[grp][8] = __builtin_amdgcn_mfma_f32_16x16x32_bf16(pf1, vones, accO[grp][8], 0, 0, 0);
            __builtin_amdgcn_s_setprio(0);
        }
        __syncthreads();   // all waves done with ldsK/ldsV before next stage
    }
    // write O, normalizing by the ones-column running sum
    #pragma unroll
    for (int grp = 0; grp < 2; ++grp) {
        float inv_l[4];
        #pragma unroll
        for (int i = 0; i < 4; ++i) inv_l[i] = 1.0f / accO[grp][8][i];
        #pragma unroll
        for (int n = 0; n < 8; ++n) {
            int gcol = h * 128 + n * 16 + c;
            #pragma unroll
            for (int i = 0; i < 4; ++i) {
                int mrow = b * SEQ + q0 + grp * 64 + wave * 16 + g * 4 + i;
                O[(size_t)mrow * 2048 + gcol] = (bf16_t)(accO[grp][n][i] * inv_l[i]);
            }
        }
    }
}

// ---------------- launch ----------------

extern "C" void kernel_launch(void* const* d_in, const int* in_sizes, int n_in,
                              void* d_out, int out_size, void* d_ws, size_t ws_size,
                              hipStream_t stream) {
    const float* x     = (const float*)d_in[0];
    const float* freqs = (const float*)d_in[1];
    const float* w_kv  = (const float*)d_in[2];
    const float* g_kv  = (const float*)d_in[3];
    const float* w_k   = (const float*)d_in[4];
    const float* w_v   = (const float*)d_in[5];
    const float* w_qn  = (const float*)d_in[6];
    const float* w_qr  = (const float*)d_in[7];
    const float* w_o   = (const float*)d_in[8];
    float* out = (float*)d_out;

    char* ws = (char*)d_ws;
    size_t off = 0;
    auto alloc = [&](size_t bytes) { char* p = ws + off; off += (bytes + 255) & ~(size_t)255; return p; };
    bf16_t* xb     = (bf16_t*)alloc((size_t)MROWS * DMODEL * 2);
    bf16_t* wkvT   = (bf16_t*)alloc((size_t)RDIM * DMODEL * 2);
    bf16_t* wkvwT  = (bf16_t*)alloc((size_t)5120 * RDIM * 2);
    bf16_t* wqT    = (bf16_t*)alloc((size_t)3072 * DMODEL * 2);
    bf16_t* woT    = (bf16_t*)alloc((size_t)DMODEL * DMODEL * 2);
    float*  kvf    = (float*) alloc((size_t)MROWS * RDIM * 4);
    bf16_t* kvb    = (bf16_t*)alloc((size_t)MROWS * RDIM * 2);
    bf16_t* kvout  = (bf16_t*)alloc((size_t)MROWS * 5120 * 2);
    bf16_t* qfull  = (bf16_t*)alloc((size_t)MROWS * 3072 * 2);
    bf16_t* vt     = (bf16_t*)alloc((size_t)32 * 128 * SEQ * 2);
    bf16_t* attno  = (bf16_t*)alloc((size_t)MROWS * 2048 * 2);
    float*  costab = (float*) alloc((size_t)SEQ * 32 * 4);
    float*  sintab = (float*) alloc((size_t)SEQ * 32 * 4);

    // prep
    cast_x_kernel<<<(MROWS * DMODEL / 4) / 256, 256, 0, stream>>>(x, xb);
    wtrans_kernel<<<dim3(RDIM / 32, DMODEL / 32), 256, 0, stream>>>(w_kv, wkvT, DMODEL, RDIM);
    wtrans_kernel<<<dim3(3072 / 32, RDIM / 32), 256, 0, stream>>>(w_k, wkvwT, RDIM, 3072);
    wtrans_kernel<<<dim3(2048 / 32, RDIM / 32), 256, 0, stream>>>(w_v, wkvwT + (size_t)3072 * RDIM, RDIM, 2048);
    wtrans_kernel<<<dim3(2048 / 32, DMODEL / 32), 256, 0, stream>>>(w_qn, wqT, DMODEL, 2048);
    wtrans_kernel<<<dim3(1024 / 32, DMODEL / 32), 256, 0, stream>>>(w_qr, wqT + (size_t)2048 * DMODEL, DMODEL, 1024);
    wtrans_kernel<<<dim3(2048 / 32, DMODEL / 32), 256, 0, stream>>>(w_o, woT, DMODEL, 2048);
    rope_table_kernel<<<(SEQ * 32) / 256, 256, 0, stream>>>(freqs, costab, sintab);

    // G1: kv_pre = x @ w_kv   (f32 out for rmsnorm)
    gemm_bt<float, 0><<<dim3(RDIM / 128, MROWS / 128), 256, 0, stream>>>(xb, wkvT, kvf, MROWS, RDIM, DMODEL, nullptr, nullptr);
    rmsnorm_kernel<<<MROWS, 256, 0, stream>>>(kvf, g_kv, kvb);
    // G2: [k_full | v] = kv @ [w_k | w_v], rope fused on k-rope cols
    gemm_bt<bf16_t, 1><<<dim3(5120 / 128, MROWS / 128), 256, 0, stream>>>(kvb, wkvwT, kvout, MROWS, 5120, RDIM, costab, sintab);
    // G3: [q_nope | q_rope] = x @ [w_qn | w_qr], rope fused on cols >= 2048
    gemm_bt<bf16_t, 2><<<dim3(3072 / 128, MROWS / 128), 256, 0, stream>>>(xb, wqT, qfull, MROWS, 3072, DMODEL, costab, sintab);

    // v transpose only (k/q consumed in native layouts)
    pack_v_kernel<<<32 * 32, 256, 0, stream>>>(kvout, vt);

    // attention (512 blocks: 32 bh x 16 q-tiles of 128 rows)
    attn_kernel<<<512, 256, 0, stream>>>(qfull, kvout, vt, attno);

    // G4: out = attn_out @ w_o   (f32 out)
    gemm_bt<float, 0><<<dim3(2048 / 128, MROWS / 128), 256, 0, stream>>>(attno, woT, out, MROWS, 2048, DMODEL, nullptr, nullptr);
}